// Round 13
// baseline (573.051 us; speedup 1.0000x reference)
//
#include <hip/hip_runtime.h>
#include <hip/hip_fp16.h>
#include <hip/hip_cooperative_groups.h>

namespace cg = cooperative_groups;

using half8 = __attribute__((ext_vector_type(8))) _Float16;
using f32x4 = __attribute__((ext_vector_type(4))) float;

#define PCHUNK 2048  // edges per chunk-block
#define PJ 8         // PCHUNK/256
#define NBPAD 392    // padded bucket count (NB=391)

// ============ fused CSR prep: bhist -> rowscan -> nscan -> part -> build ============
// One cooperative launch replaces 5 kernels (saves 4 dispatch boundaries).
// Phase math identical to the R9 bucketed pipeline (R10 lesson: keep bucketed scatter).
__global__ __launch_bounds__(256) void k_prep(
        const int* __restrict__ src, const int* __restrict__ dst, int E, int N, int NBLK,
        int* __restrict__ rhist, int* __restrict__ rowsum, int* __restrict__ bstart,
        unsigned* __restrict__ ebuf,
        int* __restrict__ cnt, float* __restrict__ dinv, int* __restrict__ offs,
        int* __restrict__ csr, const float4* __restrict__ X4, uint2* __restrict__ Xh) {
    cg::grid_group grid = cg::this_grid();
    __shared__ int h[NBPAD];
    __shared__ int sA[NBPAD];
    __shared__ int sB[NBPAD];
    __shared__ float fd[256];

    const int NB = (N + 255) >> 8;
    const int c = blockIdx.x, t = threadIdx.x;
    const int e0 = c * PCHUNK, e1 = min(E, e0 + PCHUNK);

    // ---- phase A: per-chunk bucket histogram ----
    for (int i = t; i < NB; i += 256) h[i] = 0;
    __syncthreads();
    for (int e = e0 + t; e < e1; e += 256) {
        int d = dst[e];
        d = ((unsigned)d < (unsigned)N) ? d : 0;
        atomicAdd(&h[d >> 8], 1);
    }
    __syncthreads();
    for (int i = t; i < NB; i += 256) rhist[c * NBPAD + i] = h[i];
    grid.sync();

    // ---- phase B: per-bucket exclusive scan over chunks (blocks < NB) ----
    if (c < NB) {
        int v[4];
        int s = 0;
#pragma unroll
        for (int j = 0; j < 4; j++) {
            int cc = t * 4 + j;
            v[j] = (cc < NBLK) ? rhist[cc * NBPAD + c] : 0;
            s += v[j];
        }
        sA[t] = s;
        __syncthreads();
        for (int off = 1; off < 256; off <<= 1) {
            int x = (t >= off) ? sA[t - off] : 0;
            __syncthreads();
            sA[t] += x;
            __syncthreads();
        }
        int run = (t == 0) ? 0 : sA[t - 1];
#pragma unroll
        for (int j = 0; j < 4; j++) {
            int cc = t * 4 + j;
            if (cc < NBLK) rhist[cc * NBPAD + c] = run;
            run += v[j];
        }
        if (t == 0) rowsum[c] = sA[255];
    }
    grid.sync();

    // ---- phase C: exclusive scan of rowsum -> bstart (block 0; 2 elems/thread) ----
    if (c == 0) {
        int v0 = (2 * t < NB) ? rowsum[2 * t] : 0;
        int v1 = (2 * t + 1 < NB) ? rowsum[2 * t + 1] : 0;
        sA[t] = v0 + v1;
        __syncthreads();
        for (int off = 1; off < 256; off <<= 1) {
            int x = (t >= off) ? sA[t - off] : 0;
            __syncthreads();
            sA[t] += x;
            __syncthreads();
        }
        int run = (t == 0) ? 0 : sA[t - 1];
        if (2 * t < NB) bstart[2 * t] = run;
        if (2 * t + 1 < NB) bstart[2 * t + 1] = run + v0;
        if (t == 0) bstart[NB] = E;
    }
    grid.sync();

    // ---- phase D: partition edges into bucket-ordered ebuf (all blocks) ----
    for (int i = t; i < NB; i += 256) {
        sA[i] = bstart[i] + rhist[c * NBPAD + i];
        sB[i] = 0;
    }
    __syncthreads();
#pragma unroll
    for (int j = 0; j < PJ; j++) {
        int e = e0 + j * 256 + t;
        if (e < e1) {
            int dd = dst[e];
            dd = ((unsigned)dd < (unsigned)N) ? dd : 0;  // clamp: consistent everywhere
            int ss = src[e];
            int bk = dd >> 8;
            int pos = sA[bk] + atomicAdd(&sB[bk], 1);
            ebuf[pos] = ((unsigned)ss << 8) | ((unsigned)dd & 255u);
        }
    }
    grid.sync();

    // ---- phase E: per-bucket CSR build + fused pre-scaled X->fp16 (blocks < NB) ----
    if (c < NB) {
        int base = c << 8;
        h[t] = 0;
        __syncthreads();
        int f0 = bstart[c], f1 = bstart[c + 1];
        for (int e = f0 + t; e < f1; e += 256)
            atomicAdd(&h[ebuf[e] & 255u], 1);
        __syncthreads();
        int v = h[t];
        sA[t] = v;
        __syncthreads();
        for (int off = 1; off < 256; off <<= 1) {
            int x = (t >= off) ? sA[t - off] : 0;
            __syncthreads();
            sA[t] += x;
            __syncthreads();
        }
        int lo = f0 + sA[t] - v;  // global csr offset for node base+t
        int n = base + t;
        float dv = rsqrtf((float)(v + 1));  // +1 self-loop
        fd[t] = dv;
        if (n < N) {
            cnt[n] = v;
            offs[n] = lo;
            dinv[n] = dv;
        }
        sB[t] = 0;
        sA[t] = lo;  // own-entry write after own-entry read: race-free
        __syncthreads();
        for (int e = f0 + t; e < f1; e += 256) {
            unsigned p = ebuf[e];
            int ld = p & 255u;
            int pos = atomicAdd(&sB[ld], 1);
            csr[sA[ld] + pos] = (int)(p >> 8);
        }
        __syncthreads();
        // fused conversion: Xh[n] = fp16(dinv[n] * X[n]) for this bucket's nodes
        int nmax = min(256, N - base);
        if (nmax > 0) {
            const float4* Xrow = X4 + (size_t)base * 16;
            uint2* Xout = Xh + (size_t)base * 16;
            for (int u = t; u < nmax * 16; u += 256) {
                float4 vx = Xrow[u];
                float dn = fd[u >> 4];
                __half2 lo2 = __floats2half2_rn(dn * vx.x, dn * vx.y);
                __half2 hi2 = __floats2half2_rn(dn * vx.z, dn * vx.w);
                uint2 o;
                o.x = *(unsigned*)&lo2;
                o.y = *(unsigned*)&hi2;
                Xout[u] = o;
            }
        }
    }
}

// ---------------- layer-1 aggregation (pre-scaled fp16 gather, 8 lanes/node) ----------------
__device__ __forceinline__ void acc8(float a[8], uint4 p, float w) {
    __half2 h0 = *(__half2*)&p.x, h1 = *(__half2*)&p.y;
    __half2 h2 = *(__half2*)&p.z, h3 = *(__half2*)&p.w;
    a[0] += w * __low2float(h0); a[1] += w * __high2float(h0);
    a[2] += w * __low2float(h1); a[3] += w * __high2float(h1);
    a[4] += w * __low2float(h2); a[5] += w * __high2float(h2);
    a[6] += w * __low2float(h3); a[7] += w * __high2float(h3);
}

__global__ __launch_bounds__(256) void k_agg1(
        const uint4* __restrict__ Xs, const float* __restrict__ dinv,
        const int* __restrict__ offs, const int* __restrict__ cnt,
        const int* __restrict__ csr, int N, uint4* __restrict__ aggXh) {
    int tid = blockIdx.x * blockDim.x + threadIdx.x;
    int n = tid >> 3;
    int f = tid & 7;
    if (n >= N) return;
    float dn = dinv[n];
    float a[8];
    {
        uint4 p = Xs[(size_t)n * 8 + f];  // self term (already dinv-scaled)
        __half2 h0 = *(__half2*)&p.x, h1 = *(__half2*)&p.y;
        __half2 h2 = *(__half2*)&p.z, h3 = *(__half2*)&p.w;
        a[0] = __low2float(h0); a[1] = __high2float(h0);
        a[2] = __low2float(h1); a[3] = __high2float(h1);
        a[4] = __low2float(h2); a[5] = __high2float(h2);
        a[6] = __low2float(h3); a[7] = __high2float(h3);
    }
    int base = offs[n], deg = cnt[n];
    int j = 0;
    int s0 = 0, s1 = 0, s2 = 0, s3 = 0;
    if (deg >= 4) {
        s0 = csr[base]; s1 = csr[base + 1]; s2 = csr[base + 2]; s3 = csr[base + 3];
        s0 = ((unsigned)s0 < (unsigned)N) ? s0 : 0;
        s1 = ((unsigned)s1 < (unsigned)N) ? s1 : 0;
        s2 = ((unsigned)s2 < (unsigned)N) ? s2 : 0;
        s3 = ((unsigned)s3 < (unsigned)N) ? s3 : 0;
    }
    for (; j + 8 <= deg; j += 4) {
        uint4 p0 = Xs[(size_t)s0 * 8 + f];
        uint4 p1 = Xs[(size_t)s1 * 8 + f];
        uint4 p2 = Xs[(size_t)s2 * 8 + f];
        uint4 p3 = Xs[(size_t)s3 * 8 + f];
        int t0 = csr[base + j + 4], t1 = csr[base + j + 5];
        int t2 = csr[base + j + 6], t3 = csr[base + j + 7];
        acc8(a, p0, 1.f);
        acc8(a, p1, 1.f);
        acc8(a, p2, 1.f);
        acc8(a, p3, 1.f);
        s0 = ((unsigned)t0 < (unsigned)N) ? t0 : 0;
        s1 = ((unsigned)t1 < (unsigned)N) ? t1 : 0;
        s2 = ((unsigned)t2 < (unsigned)N) ? t2 : 0;
        s3 = ((unsigned)t3 < (unsigned)N) ? t3 : 0;
    }
    if (j + 4 <= deg) {  // drain prefetched quartet
        uint4 p0 = Xs[(size_t)s0 * 8 + f];
        uint4 p1 = Xs[(size_t)s1 * 8 + f];
        uint4 p2 = Xs[(size_t)s2 * 8 + f];
        uint4 p3 = Xs[(size_t)s3 * 8 + f];
        acc8(a, p0, 1.f);
        acc8(a, p1, 1.f);
        acc8(a, p2, 1.f);
        acc8(a, p3, 1.f);
        j += 4;
    }
    for (; j < deg; j++) {
        int s = csr[base + j];
        s = ((unsigned)s < (unsigned)N) ? s : 0;
        uint4 p = Xs[(size_t)s * 8 + f];
        acc8(a, p, 1.f);
    }
    __half2 o0 = __floats2half2_rn(dn * a[0], dn * a[1]);
    __half2 o1 = __floats2half2_rn(dn * a[2], dn * a[3]);
    __half2 o2 = __floats2half2_rn(dn * a[4], dn * a[5]);
    __half2 o3 = __floats2half2_rn(dn * a[6], dn * a[7]);
    uint4 o;
    o.x = *(unsigned*)&o0;
    o.y = *(unsigned*)&o1;
    o.z = *(unsigned*)&o2;
    o.w = *(unsigned*)&o3;
    aggXh[(size_t)n * 8 + f] = o;
}

// ---------------- MFMA MLP (operand-swapped; conflict-free weight staging) ----------------
__global__ __launch_bounds__(256) void k_mlp(
        const _Float16* __restrict__ aggXh, const float* __restrict__ dinv,
        const float* __restrict__ Wn, const float* __restrict__ bn,
        const float* __restrict__ Ws, const float* __restrict__ bs,
        const float* __restrict__ Wf, int N, _Float16* __restrict__ Zs) {
    __shared__ half8 sB2[32 * 64];          // 32 KB
    __shared__ _Float16 Hbuf[4][16 * 136];  // 17408 B; init-time alias: row-major LWn/LWs (16 KB)
    __shared__ float sBias[256];

    const int t = threadIdx.x;
    const int l = t & 63;
    const int wid = t >> 6;
    const int q = l >> 4;
    const int n16 = l & 15;

    // ---- stage Wf -> sB2 fragment layout (vector loads, half2 LDS writes) ----
    {
        const float4* Wf4 = (const float4*)Wf;
        for (int it = t; it < 2048; it += 256) {
            int cg_ = it & 15, rp = it >> 4;  // row-pair rp -> rows 2rp, 2rp+1; cols 4cg..4cg+3
            int k0 = rp * 2;
            float4 va = Wf4[k0 * 16 + cg_];
            float4 vb = Wf4[k0 * 16 + 16 + cg_];
            int kt = k0 >> 5, qq = (k0 >> 3) & 3, j = k0 & 7;  // j even
            float ea[4] = {va.x, va.y, va.z, va.w};
            float eb[4] = {vb.x, vb.y, vb.z, vb.w};
#pragma unroll
            for (int cc = 0; cc < 4; cc++) {
                int cidx = cg_ * 4 + cc;
                int nt = cidx >> 4, nn = cidx & 15;
                int e = (kt * 4 + nt) * 64 + qq * 16 + nn;
                __half2 hh = __floats2half2_rn(ea[cc], eb[cc]);
                *(__half2*)((char*)sB2 + e * 16 + j * 2) = hh;
            }
        }
    }
    // ---- stage Wn/Ws row-major fp16 (coalesced loads, conflict-free uint2 LDS writes) ----
    _Float16* LWn = (_Float16*)Hbuf;   // [r*128 + c]
    _Float16* LWs = LWn + 4096;
    {
        const float4* Wn4 = (const float4*)Wn;
        const float4* Ws4 = (const float4*)Ws;
        for (int it = t; it < 2048; it += 256) {
            int i = it & 1023;
            float4 v = (it < 1024) ? Wn4[i] : Ws4[i];
            _Float16* LW = (it < 1024) ? LWn : LWs;
            __half2 lo = __floats2half2_rn(v.x, v.y);
            __half2 hi = __floats2half2_rn(v.z, v.w);
            uint2 o;
            o.x = *(unsigned*)&lo;
            o.y = *(unsigned*)&hi;
            *(uint2*)&LW[i * 4] = o;
        }
    }
    sBias[t] = (t < 128) ? bn[t] : bs[t - 128];
    __syncthreads();

    half8 w1n[8], w1s[8];
#pragma unroll
    for (int nt = 0; nt < 8; nt++) {
        half8 a, b;
#pragma unroll
        for (int j = 0; j < 8; j++) {
            a[j] = LWn[(q * 8 + j) * 128 + nt * 16 + n16];
            b[j] = LWs[(q * 8 + j) * 128 + nt * 16 + n16];
        }
        w1n[nt] = a;
        w1s[nt] = b;
    }
    __syncthreads();  // LWn/LWs dead; Hbuf reusable as H scratch

    const int ntiles = (N + 15) >> 4;
    const int nw = gridDim.x * 4;
    _Float16* Hw = Hbuf[wid];

    for (int tile = blockIdx.x * 4 + wid; tile < ntiles; tile += nw) {
        int nb = tile << 4;
        int node = nb + n16;
        int nodeA = (node < N) ? node : N - 1;
        float dn = dinv[nodeA];
        half8 an = *(const half8*)&aggXh[(size_t)nodeA * 64 + q * 8];
        half8 as = *(const half8*)&aggXh[(size_t)nodeA * 64 + 32 + q * 8];

        f32x4 Y[4];
#pragma unroll
        for (int i = 0; i < 4; i++) Y[i] = (f32x4){0.f, 0.f, 0.f, 0.f};

        // ---- nuc branch ----
#pragma unroll
        for (int nt = 0; nt < 8; nt++) {
            f32x4 bb = *(const f32x4*)&sBias[nt * 16 + q * 4];
            f32x4 c = __builtin_amdgcn_mfma_f32_16x16x32_f16(w1n[nt], an, bb, 0, 0, 0);
            float e0 = c[0] > 0.f ? c[0] : (__expf(c[0]) - 1.f);
            float e1 = c[1] > 0.f ? c[1] : (__expf(c[1]) - 1.f);
            float e2 = c[2] > 0.f ? c[2] : (__expf(c[2]) - 1.f);
            float e3 = c[3] > 0.f ? c[3] : (__expf(c[3]) - 1.f);
            __half2 lo = __floats2half2_rn(e0, e1), hi = __floats2half2_rn(e2, e3);
            uint2 wv;
            wv.x = *(unsigned*)&lo;
            wv.y = *(unsigned*)&hi;
            *(uint2*)&Hw[n16 * 136 + nt * 16 + q * 4] = wv;
        }
#pragma unroll
        for (int kt = 0; kt < 4; kt++) {
            half8 ha = *(const half8*)&Hw[n16 * 136 + kt * 32 + q * 8];
#pragma unroll
            for (int nt2 = 0; nt2 < 4; nt2++)
                Y[nt2] = __builtin_amdgcn_mfma_f32_16x16x32_f16(sB2[(kt * 4 + nt2) * 64 + l], ha, Y[nt2], 0, 0, 0);
        }
        // ---- surf branch (reuses Hw; in-wave DS ordering guarantees WAR safety) ----
#pragma unroll
        for (int nt = 0; nt < 8; nt++) {
            f32x4 bb = *(const f32x4*)&sBias[128 + nt * 16 + q * 4];
            f32x4 c = __builtin_amdgcn_mfma_f32_16x16x32_f16(w1s[nt], as, bb, 0, 0, 0);
            float e0 = c[0] > 0.f ? c[0] : (__expf(c[0]) - 1.f);
            float e1 = c[1] > 0.f ? c[1] : (__expf(c[1]) - 1.f);
            float e2 = c[2] > 0.f ? c[2] : (__expf(c[2]) - 1.f);
            float e3 = c[3] > 0.f ? c[3] : (__expf(c[3]) - 1.f);
            __half2 lo = __floats2half2_rn(e0, e1), hi = __floats2half2_rn(e2, e3);
            uint2 wv;
            wv.x = *(unsigned*)&lo;
            wv.y = *(unsigned*)&hi;
            *(uint2*)&Hw[n16 * 136 + nt * 16 + q * 4] = wv;
        }
#pragma unroll
        for (int kt = 0; kt < 4; kt++) {
            half8 ha = *(const half8*)&Hw[n16 * 136 + kt * 32 + q * 8];
#pragma unroll
            for (int nt2 = 0; nt2 < 4; nt2++)
                Y[nt2] = __builtin_amdgcn_mfma_f32_16x16x32_f16(sB2[((4 + kt) * 4 + nt2) * 64 + l], ha, Y[nt2], 0, 0, 0);
        }
        // ---- Z store: lane-local node, 4 consecutive out-feats per store ----
        if (node < N) {
#pragma unroll
            for (int nt2 = 0; nt2 < 4; nt2++) {
                __half2 lo = __floats2half2_rn(dn * Y[nt2][0], dn * Y[nt2][1]);
                __half2 hi = __floats2half2_rn(dn * Y[nt2][2], dn * Y[nt2][3]);
                uint2 o;
                o.x = *(unsigned*)&lo;
                o.y = *(unsigned*)&hi;
                *(uint2*)&Zs[(size_t)node * 64 + nt2 * 16 + q * 4] = o;
            }
        }
    }
}

// ---------------- layer-2 aggregation + bias + softmax (8 lanes/node, pipelined) ----------------
__global__ __launch_bounds__(256) void k_agg2(
        const uint4* __restrict__ Zu, const float* __restrict__ dinv,
        const int* __restrict__ offs, const int* __restrict__ cnt,
        const int* __restrict__ csr, const float4* __restrict__ bias4,
        int N, f32x4* __restrict__ out4) {
    int tid = blockIdx.x * blockDim.x + threadIdx.x;
    int n = tid >> 3;
    int f = tid & 7;
    if (n >= N) return;
    float a[8];
    {
        uint4 p = Zu[(size_t)n * 8 + f];
        __half2 h0 = *(__half2*)&p.x, h1 = *(__half2*)&p.y;
        __half2 h2 = *(__half2*)&p.z, h3 = *(__half2*)&p.w;
        a[0] = __low2float(h0); a[1] = __high2float(h0);
        a[2] = __low2float(h1); a[3] = __high2float(h1);
        a[4] = __low2float(h2); a[5] = __high2float(h2);
        a[6] = __low2float(h3); a[7] = __high2float(h3);
    }
    int base = offs[n], deg = cnt[n];
    int j = 0;
    int s0 = 0, s1 = 0, s2 = 0, s3 = 0;
    if (deg >= 4) {
        s0 = csr[base]; s1 = csr[base + 1]; s2 = csr[base + 2]; s3 = csr[base + 3];
        s0 = ((unsigned)s0 < (unsigned)N) ? s0 : 0;
        s1 = ((unsigned)s1 < (unsigned)N) ? s1 : 0;
        s2 = ((unsigned)s2 < (unsigned)N) ? s2 : 0;
        s3 = ((unsigned)s3 < (unsigned)N) ? s3 : 0;
    }
    for (; j + 8 <= deg; j += 4) {
        uint4 p0 = Zu[(size_t)s0 * 8 + f];
        uint4 p1 = Zu[(size_t)s1 * 8 + f];
        uint4 p2 = Zu[(size_t)s2 * 8 + f];
        uint4 p3 = Zu[(size_t)s3 * 8 + f];
        int t0 = csr[base + j + 4], t1 = csr[base + j + 5];
        int t2 = csr[base + j + 6], t3 = csr[base + j + 7];
        acc8(a, p0, 1.f);
        acc8(a, p1, 1.f);
        acc8(a, p2, 1.f);
        acc8(a, p3, 1.f);
        s0 = ((unsigned)t0 < (unsigned)N) ? t0 : 0;
        s1 = ((unsigned)t1 < (unsigned)N) ? t1 : 0;
        s2 = ((unsigned)t2 < (unsigned)N) ? t2 : 0;
        s3 = ((unsigned)t3 < (unsigned)N) ? t3 : 0;
    }
    if (j + 4 <= deg) {  // drain prefetched quartet
        uint4 p0 = Zu[(size_t)s0 * 8 + f];
        uint4 p1 = Zu[(size_t)s1 * 8 + f];
        uint4 p2 = Zu[(size_t)s2 * 8 + f];
        uint4 p3 = Zu[(size_t)s3 * 8 + f];
        acc8(a, p0, 1.f);
        acc8(a, p1, 1.f);
        acc8(a, p2, 1.f);
        acc8(a, p3, 1.f);
        j += 4;
    }
    for (; j < deg; j++) {
        int s = csr[base + j];
        s = ((unsigned)s < (unsigned)N) ? s : 0;
        uint4 p = Zu[(size_t)s * 8 + f];
        acc8(a, p, 1.f);
    }
    float dn = dinv[n];
    float4 b0 = bias4[f * 2], b1 = bias4[f * 2 + 1];
    a[0] = dn * a[0] + b0.x; a[1] = dn * a[1] + b0.y;
    a[2] = dn * a[2] + b0.z; a[3] = dn * a[3] + b0.w;
    a[4] = dn * a[4] + b1.x; a[5] = dn * a[5] + b1.y;
    a[6] = dn * a[6] + b1.z; a[7] = dn * a[7] + b1.w;
    float mx = a[0];
#pragma unroll
    for (int k = 1; k < 8; k++) mx = fmaxf(mx, a[k]);
    for (int o = 4; o >= 1; o >>= 1) mx = fmaxf(mx, __shfl_xor(mx, o));
    float e[8];
    float sm = 0.f;
#pragma unroll
    for (int k = 0; k < 8; k++) { e[k] = expf(a[k] - mx); sm += e[k]; }
    for (int o = 4; o >= 1; o >>= 1) sm += __shfl_xor(sm, o);
    float inv = 1.f / sm;
    f32x4 o0 = {e[0] * inv, e[1] * inv, e[2] * inv, e[3] * inv};
    f32x4 o1 = {e[4] * inv, e[5] * inv, e[6] * inv, e[7] * inv};
    __builtin_nontemporal_store(o0, &out4[(size_t)n * 16 + f * 2]);
    __builtin_nontemporal_store(o1, &out4[(size_t)n * 16 + f * 2 + 1]);
}

extern "C" void kernel_launch(void* const* d_in, const int* in_sizes, int n_in,
                              void* d_out, int out_size, void* d_ws, size_t ws_size,
                              hipStream_t stream) {
    const float* X = (const float*)d_in[0];
    const int* ei = (const int*)d_in[1];
    // d_in[2] = batch (unused)
    const float* Wn = (const float*)d_in[3];
    const float* bn = (const float*)d_in[4];
    const float* Ws = (const float*)d_in[5];
    const float* bs = (const float*)d_in[6];
    const float* Wf = (const float*)d_in[7];
    const float* bfu = (const float*)d_in[8];

    int N = in_sizes[2];        // 100000
    int E = in_sizes[1] / 2;    // 1600000
    const int* src = ei;
    const int* dst = ei + E;
    const int NB = (N + 255) >> 8;    // 391 buckets
    int NBLK = (E + PCHUNK - 1) / PCHUNK;  // 782 chunk-blocks (co-resident: 782*4 waves << 8192)

    // workspace layout (same 33.2MB footprint)
    char* ws = (char*)d_ws;
    int* rowsum   = (int*)(ws + 0);            // NB*4
    int* bstart   = (int*)(ws + 12800);        // (NB+1)*4 -> pad 14464
    int* cnt      = (int*)(ws + 14464);        // 400000 -> 414464
    float* dinv   = (float*)(ws + 414464);     // 400000 -> 814464
    int* offs     = (int*)(ws + 814464);       // 400000 -> 1214464
    int* csr      = (int*)(ws + 1214464);      // 6400000 -> 7614464
    // rhist aliases csr: rhist dead (phase D) before csr written (phase E); grid.sync separates.
    int* rhist    = (int*)(ws + 1214464);
    // slot A: ebuf (phase D/E), then aggXh (agg1 -> mlp)
    unsigned* ebuf = (unsigned*)(ws + 7614464);
    uint4* aggXh  = (uint4*)(ws + 7614464);
    // slot B: Xh (phase E tail -> agg1), then Zs (mlp -> agg2)
    uint2* Xh     = (uint2*)(ws + 20414464);   // 12800000 -> 33214464 total
    _Float16* Zs  = (_Float16*)(ws + 20414464);

    const float4* X4p = (const float4*)X;
    void* args[] = {(void*)&src, (void*)&dst, (void*)&E, (void*)&N, (void*)&NBLK,
                    (void*)&rhist, (void*)&rowsum, (void*)&bstart, (void*)&ebuf,
                    (void*)&cnt, (void*)&dinv, (void*)&offs, (void*)&csr,
                    (void*)&X4p, (void*)&Xh};
    hipLaunchCooperativeKernel((const void*)k_prep, dim3(NBLK), dim3(256), args, 0, stream);

    int gbl = (N * 8 + 255) / 256;  // 8 lanes per node
    k_agg1<<<gbl, 256, 0, stream>>>((const uint4*)Xh, dinv, offs, cnt, csr, N, aggXh);
    k_mlp<<<512, 256, 0, stream>>>((const _Float16*)aggXh, dinv, Wn, bn, Ws, bs, Wf, N, Zs);
    k_agg2<<<gbl, 256, 0, stream>>>((const uint4*)Zs, dinv, offs, cnt, csr,
                                    (const float4*)bfu, N, (f32x4*)d_out);
}

// Round 14
// 230.418 us; speedup vs baseline: 2.4870x; 2.4870x over previous
//
#include <hip/hip_runtime.h>
#include <hip/hip_fp16.h>

using half8 = __attribute__((ext_vector_type(8))) _Float16;
using f32x4 = __attribute__((ext_vector_type(4))) float;

#define PCHUNK 2048  // edges per chunk-block
#define PJ 8         // PCHUNK/256
#define NBPAD 392    // padded bucket count (NB=391)

// ============ bucketed CSR build, atomic-free partition ============
// R10 lesson: node-level flat scatter = 106MB random write-allocate HBM traffic (137us) -> keep
// bucketed LDS-cursor scatter. R13 lesson: cooperative grid.sync costs ~100us/sync on 8-XCD
// MI355X (non-coherent L2 drain) -> keep separate kernel launches.

__global__ __launch_bounds__(256) void k_bhist(const int* __restrict__ dst, int E, int N,
                                               int* __restrict__ rhist) {
    __shared__ int h[NBPAD];
    const int NB = (N + 255) >> 8;
    int c = blockIdx.x, t = threadIdx.x;
    for (int i = t; i < NB; i += 256) h[i] = 0;
    __syncthreads();
    int e0 = c * PCHUNK, e1 = min(E, e0 + PCHUNK);
    for (int e = e0 + t; e < e1; e += 256) {
        int d = dst[e];
        d = ((unsigned)d < (unsigned)N) ? d : 0;
        atomicAdd(&h[d >> 8], 1);
    }
    __syncthreads();
    for (int i = t; i < NB; i += 256) rhist[c * NBPAD + i] = h[i];  // coalesced store
}

// per-bucket exclusive scan over chunks: block b scans rhist[c*NBPAD+b], c=0..NBLK-1 (NBLK<=1024)
__global__ __launch_bounds__(256) void k_rowscan(int* __restrict__ rhist, int NBLK,
                                                 int* __restrict__ rowsum) {
    __shared__ int sd[256];
    int b = blockIdx.x, t = threadIdx.x;
    int v[4];
    int s = 0;
#pragma unroll
    for (int j = 0; j < 4; j++) {
        int c = t * 4 + j;
        v[j] = (c < NBLK) ? rhist[c * NBPAD + b] : 0;
        s += v[j];
    }
    sd[t] = s;
    __syncthreads();
    for (int off = 1; off < 256; off <<= 1) {
        int x = (t >= off) ? sd[t - off] : 0;
        __syncthreads();
        sd[t] += x;
        __syncthreads();
    }
    int run = (t == 0) ? 0 : sd[t - 1];
#pragma unroll
    for (int j = 0; j < 4; j++) {
        int c = t * 4 + j;
        if (c < NBLK) rhist[c * NBPAD + b] = run;
        run += v[j];
    }
    if (t == 0) rowsum[b] = sd[255];
}

// exclusive scan of rowsum[NB] -> bstart[0..NB], bstart[NB]=E  (single block)
__global__ void k_nscan(const int* __restrict__ rowsum, int NB, int E, int* __restrict__ bstart) {
    __shared__ int sd[512];
    int t = threadIdx.x;
    int v = (t < NB) ? rowsum[t] : 0;
    sd[t] = v;
    __syncthreads();
    for (int off = 1; off < 512; off <<= 1) {
        int x = (t >= off) ? sd[t - off] : 0;
        __syncthreads();
        sd[t] += x;
        __syncthreads();
    }
    if (t < NB) bstart[t] = sd[t] - v;
    if (t == 0) bstart[NB] = E;
}

// one pass, one barrier, zero global atomics
__global__ __launch_bounds__(256) void k_part(const int* __restrict__ src, const int* __restrict__ dst,
                                              int E, int N, const int* __restrict__ rhist,
                                              const int* __restrict__ bstart,
                                              unsigned* __restrict__ ebuf) {
    __shared__ int lbase[NBPAD], lcnt[NBPAD];
    const int NB = (N + 255) >> 8;
    int c = blockIdx.x, t = threadIdx.x;
    for (int i = t; i < NB; i += 256) {
        lbase[i] = bstart[i] + rhist[c * NBPAD + i];  // coalesced load
        lcnt[i] = 0;
    }
    __syncthreads();
    int e0 = c * PCHUNK, e1 = min(E, e0 + PCHUNK);
#pragma unroll
    for (int j = 0; j < PJ; j++) {
        int e = e0 + j * 256 + t;
        if (e < e1) {
            int dd = dst[e];
            dd = ((unsigned)dd < (unsigned)N) ? dd : 0;  // clamp: consistent everywhere
            int ss = src[e];
            int bk = dd >> 8;
            int pos = lbase[bk] + atomicAdd(&lcnt[bk], 1);
            ebuf[pos] = ((unsigned)ss << 8) | ((unsigned)dd & 255u);
        }
    }
}

// one block per bucket: LDS degree hist -> local scan -> write cnt/offs/dinv -> LDS-cursor CSR
// scatter -> fused scaled X->fp16 conversion of THIS bucket's rows (dinv from LDS, race-free).
__global__ __launch_bounds__(256) void k_build(const unsigned* __restrict__ ebuf,
                                               const int* __restrict__ bstart, int N,
                                               int* __restrict__ cnt, float* __restrict__ dinv,
                                               int* __restrict__ offs, int* __restrict__ csr,
                                               const float4* __restrict__ X4,
                                               uint2* __restrict__ Xh) {
    __shared__ int h[256], sc[256], lcur[256];
    __shared__ float fdinv[256];
    int b = blockIdx.x, t = threadIdx.x;
    int base = b << 8;
    h[t] = 0;
    __syncthreads();
    int e0 = bstart[b], e1 = bstart[b + 1];
    for (int e = e0 + t; e < e1; e += 256)
        atomicAdd(&h[ebuf[e] & 255u], 1);
    __syncthreads();
    int v = h[t];
    sc[t] = v;
    __syncthreads();
    for (int off = 1; off < 256; off <<= 1) {
        int x = (t >= off) ? sc[t - off] : 0;
        __syncthreads();
        sc[t] += x;
        __syncthreads();
    }
    int lo = e0 + sc[t] - v;  // global csr offset for node base+t
    int n = base + t;
    float dv = rsqrtf((float)(v + 1));  // +1 self-loop
    fdinv[t] = dv;
    if (n < N) {
        cnt[n] = v;
        offs[n] = lo;
        dinv[n] = dv;
    }
    lcur[t] = 0;
    sc[t] = lo;  // reuse as lofs (own-entry write after own-entry read: race-free)
    __syncthreads();
    for (int e = e0 + t; e < e1; e += 256) {
        unsigned p = ebuf[e];
        int ld = p & 255u;
        int pos = atomicAdd(&lcur[ld], 1);
        csr[sc[ld] + pos] = (int)(p >> 8);
    }
    __syncthreads();  // fdinv fully written (before scatter); all threads past scatter
    // fused conversion: Xh[n] = fp16(dinv[n] * X[n]) for this bucket's nodes only
    int nmax = min(256, N - base);
    if (nmax > 0) {
        const float4* Xrow = X4 + (size_t)base * 16;
        uint2* Xout = Xh + (size_t)base * 16;
        for (int u = t; u < nmax * 16; u += 256) {
            float4 vx = Xrow[u];
            float dn = fdinv[u >> 4];
            __half2 lo2 = __floats2half2_rn(dn * vx.x, dn * vx.y);
            __half2 hi2 = __floats2half2_rn(dn * vx.z, dn * vx.w);
            uint2 o;
            o.x = *(unsigned*)&lo2;
            o.y = *(unsigned*)&hi2;
            Xout[u] = o;
        }
    }
}

// ---------------- layer-1 aggregation (pre-scaled fp16 gather, 8 lanes/node) ----------------
// Xs rows are pre-scaled by dinv: agg[n] = dn * (Xs[n] + sum Xs[s]) -- no per-edge dinv loads.
__device__ __forceinline__ void acc8(float a[8], uint4 p, float w) {
    __half2 h0 = *(__half2*)&p.x, h1 = *(__half2*)&p.y;
    __half2 h2 = *(__half2*)&p.z, h3 = *(__half2*)&p.w;
    a[0] += w * __low2float(h0); a[1] += w * __high2float(h0);
    a[2] += w * __low2float(h1); a[3] += w * __high2float(h1);
    a[4] += w * __low2float(h2); a[5] += w * __high2float(h2);
    a[6] += w * __low2float(h3); a[7] += w * __high2float(h3);
}

__global__ __launch_bounds__(256) void k_agg1(
        const uint4* __restrict__ Xs, const float* __restrict__ dinv,
        const int* __restrict__ offs, const int* __restrict__ cnt,
        const int* __restrict__ csr, int N, uint4* __restrict__ aggXh) {
    int tid = blockIdx.x * blockDim.x + threadIdx.x;
    int n = tid >> 3;
    int f = tid & 7;
    if (n >= N) return;
    float dn = dinv[n];
    float a[8];
    {
        uint4 p = Xs[(size_t)n * 8 + f];  // self term (already dinv-scaled)
        __half2 h0 = *(__half2*)&p.x, h1 = *(__half2*)&p.y;
        __half2 h2 = *(__half2*)&p.z, h3 = *(__half2*)&p.w;
        a[0] = __low2float(h0); a[1] = __high2float(h0);
        a[2] = __low2float(h1); a[3] = __high2float(h1);
        a[4] = __low2float(h2); a[5] = __high2float(h2);
        a[6] = __low2float(h3); a[7] = __high2float(h3);
    }
    int base = offs[n], deg = cnt[n];
    int j = 0;
    int s0 = 0, s1 = 0, s2 = 0, s3 = 0;
    if (deg >= 4) {
        s0 = csr[base]; s1 = csr[base + 1]; s2 = csr[base + 2]; s3 = csr[base + 3];
        s0 = ((unsigned)s0 < (unsigned)N) ? s0 : 0;
        s1 = ((unsigned)s1 < (unsigned)N) ? s1 : 0;
        s2 = ((unsigned)s2 < (unsigned)N) ? s2 : 0;
        s3 = ((unsigned)s3 < (unsigned)N) ? s3 : 0;
    }
    for (; j + 8 <= deg; j += 4) {
        uint4 p0 = Xs[(size_t)s0 * 8 + f];
        uint4 p1 = Xs[(size_t)s1 * 8 + f];
        uint4 p2 = Xs[(size_t)s2 * 8 + f];
        uint4 p3 = Xs[(size_t)s3 * 8 + f];
        int t0 = csr[base + j + 4], t1 = csr[base + j + 5];
        int t2 = csr[base + j + 6], t3 = csr[base + j + 7];
        acc8(a, p0, 1.f);
        acc8(a, p1, 1.f);
        acc8(a, p2, 1.f);
        acc8(a, p3, 1.f);
        s0 = ((unsigned)t0 < (unsigned)N) ? t0 : 0;
        s1 = ((unsigned)t1 < (unsigned)N) ? t1 : 0;
        s2 = ((unsigned)t2 < (unsigned)N) ? t2 : 0;
        s3 = ((unsigned)t3 < (unsigned)N) ? t3 : 0;
    }
    if (j + 4 <= deg) {  // drain prefetched quartet
        uint4 p0 = Xs[(size_t)s0 * 8 + f];
        uint4 p1 = Xs[(size_t)s1 * 8 + f];
        uint4 p2 = Xs[(size_t)s2 * 8 + f];
        uint4 p3 = Xs[(size_t)s3 * 8 + f];
        acc8(a, p0, 1.f);
        acc8(a, p1, 1.f);
        acc8(a, p2, 1.f);
        acc8(a, p3, 1.f);
        j += 4;
    }
    for (; j < deg; j++) {
        int s = csr[base + j];
        s = ((unsigned)s < (unsigned)N) ? s : 0;
        uint4 p = Xs[(size_t)s * 8 + f];
        acc8(a, p, 1.f);
    }
    __half2 o0 = __floats2half2_rn(dn * a[0], dn * a[1]);
    __half2 o1 = __floats2half2_rn(dn * a[2], dn * a[3]);
    __half2 o2 = __floats2half2_rn(dn * a[4], dn * a[5]);
    __half2 o3 = __floats2half2_rn(dn * a[6], dn * a[7]);
    uint4 o;
    o.x = *(unsigned*)&o0;
    o.y = *(unsigned*)&o1;
    o.z = *(unsigned*)&o2;
    o.w = *(unsigned*)&o3;
    aggXh[(size_t)n * 8 + f] = o;
}

// ---------------- MFMA MLP (operand-swapped; conflict-free weight staging) ----------------
__global__ __launch_bounds__(256) void k_mlp(
        const _Float16* __restrict__ aggXh, const float* __restrict__ dinv,
        const float* __restrict__ Wn, const float* __restrict__ bn,
        const float* __restrict__ Ws, const float* __restrict__ bs,
        const float* __restrict__ Wf, int N, _Float16* __restrict__ Zs) {
    __shared__ half8 sB2[32 * 64];          // 32 KB
    __shared__ _Float16 Hbuf[4][16 * 136];  // 17408 B; init-time alias: row-major LWn/LWs (16 KB)
    __shared__ float sBias[256];

    const int t = threadIdx.x;
    const int l = t & 63;
    const int wid = t >> 6;
    const int q = l >> 4;
    const int n16 = l & 15;

    // ---- stage Wf -> sB2 fragment layout (vector loads, half2 LDS writes) ----
    {
        const float4* Wf4 = (const float4*)Wf;
        for (int it = t; it < 2048; it += 256) {
            int cg = it & 15, rp = it >> 4;  // row-pair rp -> rows 2rp, 2rp+1; cols 4cg..4cg+3
            int k0 = rp * 2;
            float4 va = Wf4[k0 * 16 + cg];
            float4 vb = Wf4[k0 * 16 + 16 + cg];
            int kt = k0 >> 5, qq = (k0 >> 3) & 3, j = k0 & 7;  // j even
            float ea[4] = {va.x, va.y, va.z, va.w};
            float eb[4] = {vb.x, vb.y, vb.z, vb.w};
#pragma unroll
            for (int cc = 0; cc < 4; cc++) {
                int c = cg * 4 + cc;
                int nt = c >> 4, nn = c & 15;
                int e = (kt * 4 + nt) * 64 + qq * 16 + nn;
                __half2 h = __floats2half2_rn(ea[cc], eb[cc]);
                *(__half2*)((char*)sB2 + e * 16 + j * 2) = h;
            }
        }
    }
    // ---- stage Wn/Ws row-major fp16 (coalesced loads, conflict-free uint2 LDS writes) ----
    _Float16* LWn = (_Float16*)Hbuf;   // [r*128 + c]
    _Float16* LWs = LWn + 4096;
    {
        const float4* Wn4 = (const float4*)Wn;
        const float4* Ws4 = (const float4*)Ws;
        for (int it = t; it < 2048; it += 256) {
            int i = it & 1023;
            float4 v = (it < 1024) ? Wn4[i] : Ws4[i];
            _Float16* LW = (it < 1024) ? LWn : LWs;
            __half2 lo = __floats2half2_rn(v.x, v.y);
            __half2 hi = __floats2half2_rn(v.z, v.w);
            uint2 o;
            o.x = *(unsigned*)&lo;
            o.y = *(unsigned*)&hi;
            *(uint2*)&LW[i * 4] = o;
        }
    }
    sBias[t] = (t < 128) ? bn[t] : bs[t - 128];
    __syncthreads();

    half8 w1n[8], w1s[8];
#pragma unroll
    for (int nt = 0; nt < 8; nt++) {
        half8 a, b;
#pragma unroll
        for (int j = 0; j < 8; j++) {
            a[j] = LWn[(q * 8 + j) * 128 + nt * 16 + n16];
            b[j] = LWs[(q * 8 + j) * 128 + nt * 16 + n16];
        }
        w1n[nt] = a;
        w1s[nt] = b;
    }
    __syncthreads();  // LWn/LWs dead; Hbuf reusable as H scratch

    const int ntiles = (N + 15) >> 4;
    const int nw = gridDim.x * 4;
    _Float16* Hw = Hbuf[wid];

    for (int tile = blockIdx.x * 4 + wid; tile < ntiles; tile += nw) {
        int nb = tile << 4;
        int node = nb + n16;
        int nodeA = (node < N) ? node : N - 1;
        float dn = dinv[nodeA];
        half8 an = *(const half8*)&aggXh[(size_t)nodeA * 64 + q * 8];
        half8 as = *(const half8*)&aggXh[(size_t)nodeA * 64 + 32 + q * 8];

        f32x4 Y[4];
#pragma unroll
        for (int i = 0; i < 4; i++) Y[i] = (f32x4){0.f, 0.f, 0.f, 0.f};

        // ---- nuc branch ----
#pragma unroll
        for (int nt = 0; nt < 8; nt++) {
            f32x4 bb = *(const f32x4*)&sBias[nt * 16 + q * 4];
            f32x4 c = __builtin_amdgcn_mfma_f32_16x16x32_f16(w1n[nt], an, bb, 0, 0, 0);
            float e0 = c[0] > 0.f ? c[0] : (__expf(c[0]) - 1.f);
            float e1 = c[1] > 0.f ? c[1] : (__expf(c[1]) - 1.f);
            float e2 = c[2] > 0.f ? c[2] : (__expf(c[2]) - 1.f);
            float e3 = c[3] > 0.f ? c[3] : (__expf(c[3]) - 1.f);
            __half2 lo = __floats2half2_rn(e0, e1), hi = __floats2half2_rn(e2, e3);
            uint2 wv;
            wv.x = *(unsigned*)&lo;
            wv.y = *(unsigned*)&hi;
            *(uint2*)&Hw[n16 * 136 + nt * 16 + q * 4] = wv;
        }
#pragma unroll
        for (int kt = 0; kt < 4; kt++) {
            half8 ha = *(const half8*)&Hw[n16 * 136 + kt * 32 + q * 8];
#pragma unroll
            for (int nt2 = 0; nt2 < 4; nt2++)
                Y[nt2] = __builtin_amdgcn_mfma_f32_16x16x32_f16(sB2[(kt * 4 + nt2) * 64 + l], ha, Y[nt2], 0, 0, 0);
        }
        // ---- surf branch (reuses Hw; in-wave DS ordering guarantees WAR safety) ----
#pragma unroll
        for (int nt = 0; nt < 8; nt++) {
            f32x4 bb = *(const f32x4*)&sBias[128 + nt * 16 + q * 4];
            f32x4 c = __builtin_amdgcn_mfma_f32_16x16x32_f16(w1s[nt], as, bb, 0, 0, 0);
            float e0 = c[0] > 0.f ? c[0] : (__expf(c[0]) - 1.f);
            float e1 = c[1] > 0.f ? c[1] : (__expf(c[1]) - 1.f);
            float e2 = c[2] > 0.f ? c[2] : (__expf(c[2]) - 1.f);
            float e3 = c[3] > 0.f ? c[3] : (__expf(c[3]) - 1.f);
            __half2 lo = __floats2half2_rn(e0, e1), hi = __floats2half2_rn(e2, e3);
            uint2 wv;
            wv.x = *(unsigned*)&lo;
            wv.y = *(unsigned*)&hi;
            *(uint2*)&Hw[n16 * 136 + nt * 16 + q * 4] = wv;
        }
#pragma unroll
        for (int kt = 0; kt < 4; kt++) {
            half8 ha = *(const half8*)&Hw[n16 * 136 + kt * 32 + q * 8];
#pragma unroll
            for (int nt2 = 0; nt2 < 4; nt2++)
                Y[nt2] = __builtin_amdgcn_mfma_f32_16x16x32_f16(sB2[((4 + kt) * 4 + nt2) * 64 + l], ha, Y[nt2], 0, 0, 0);
        }
        // ---- Z store: lane-local node, 4 consecutive out-feats per store ----
        if (node < N) {
#pragma unroll
            for (int nt2 = 0; nt2 < 4; nt2++) {
                __half2 lo = __floats2half2_rn(dn * Y[nt2][0], dn * Y[nt2][1]);
                __half2 hi = __floats2half2_rn(dn * Y[nt2][2], dn * Y[nt2][3]);
                uint2 o;
                o.x = *(unsigned*)&lo;
                o.y = *(unsigned*)&hi;
                *(uint2*)&Zs[(size_t)node * 64 + nt2 * 16 + q * 4] = o;
            }
        }
    }
}

// ---------------- layer-2 aggregation + bias + softmax (8 lanes/node, pipelined) ----------------
__global__ __launch_bounds__(256) void k_agg2(
        const uint4* __restrict__ Zu, const float* __restrict__ dinv,
        const int* __restrict__ offs, const int* __restrict__ cnt,
        const int* __restrict__ csr, const float4* __restrict__ bias4,
        int N, f32x4* __restrict__ out4) {
    int tid = blockIdx.x * blockDim.x + threadIdx.x;
    int n = tid >> 3;
    int f = tid & 7;
    if (n >= N) return;
    float a[8];
    {
        uint4 p = Zu[(size_t)n * 8 + f];
        __half2 h0 = *(__half2*)&p.x, h1 = *(__half2*)&p.y;
        __half2 h2 = *(__half2*)&p.z, h3 = *(__half2*)&p.w;
        a[0] = __low2float(h0); a[1] = __high2float(h0);
        a[2] = __low2float(h1); a[3] = __high2float(h1);
        a[4] = __low2float(h2); a[5] = __high2float(h2);
        a[6] = __low2float(h3); a[7] = __high2float(h3);
    }
    int base = offs[n], deg = cnt[n];
    int j = 0;
    int s0 = 0, s1 = 0, s2 = 0, s3 = 0;
    if (deg >= 4) {
        s0 = csr[base]; s1 = csr[base + 1]; s2 = csr[base + 2]; s3 = csr[base + 3];
        s0 = ((unsigned)s0 < (unsigned)N) ? s0 : 0;
        s1 = ((unsigned)s1 < (unsigned)N) ? s1 : 0;
        s2 = ((unsigned)s2 < (unsigned)N) ? s2 : 0;
        s3 = ((unsigned)s3 < (unsigned)N) ? s3 : 0;
    }
    for (; j + 8 <= deg; j += 4) {
        uint4 p0 = Zu[(size_t)s0 * 8 + f];
        uint4 p1 = Zu[(size_t)s1 * 8 + f];
        uint4 p2 = Zu[(size_t)s2 * 8 + f];
        uint4 p3 = Zu[(size_t)s3 * 8 + f];
        int t0 = csr[base + j + 4], t1 = csr[base + j + 5];
        int t2 = csr[base + j + 6], t3 = csr[base + j + 7];
        acc8(a, p0, 1.f);
        acc8(a, p1, 1.f);
        acc8(a, p2, 1.f);
        acc8(a, p3, 1.f);
        s0 = ((unsigned)t0 < (unsigned)N) ? t0 : 0;
        s1 = ((unsigned)t1 < (unsigned)N) ? t1 : 0;
        s2 = ((unsigned)t2 < (unsigned)N) ? t2 : 0;
        s3 = ((unsigned)t3 < (unsigned)N) ? t3 : 0;
    }
    if (j + 4 <= deg) {  // drain prefetched quartet
        uint4 p0 = Zu[(size_t)s0 * 8 + f];
        uint4 p1 = Zu[(size_t)s1 * 8 + f];
        uint4 p2 = Zu[(size_t)s2 * 8 + f];
        uint4 p3 = Zu[(size_t)s3 * 8 + f];
        acc8(a, p0, 1.f);
        acc8(a, p1, 1.f);
        acc8(a, p2, 1.f);
        acc8(a, p3, 1.f);
        j += 4;
    }
    for (; j < deg; j++) {
        int s = csr[base + j];
        s = ((unsigned)s < (unsigned)N) ? s : 0;
        uint4 p = Zu[(size_t)s * 8 + f];
        acc8(a, p, 1.f);
    }
    float dn = dinv[n];
    float4 b0 = bias4[f * 2], b1 = bias4[f * 2 + 1];
    a[0] = dn * a[0] + b0.x; a[1] = dn * a[1] + b0.y;
    a[2] = dn * a[2] + b0.z; a[3] = dn * a[3] + b0.w;
    a[4] = dn * a[4] + b1.x; a[5] = dn * a[5] + b1.y;
    a[6] = dn * a[6] + b1.z; a[7] = dn * a[7] + b1.w;
    float mx = a[0];
#pragma unroll
    for (int k = 1; k < 8; k++) mx = fmaxf(mx, a[k]);
    for (int o = 4; o >= 1; o >>= 1) mx = fmaxf(mx, __shfl_xor(mx, o));
    float e[8];
    float sm = 0.f;
#pragma unroll
    for (int k = 0; k < 8; k++) { e[k] = expf(a[k] - mx); sm += e[k]; }
    for (int o = 4; o >= 1; o >>= 1) sm += __shfl_xor(sm, o);
    float inv = 1.f / sm;
    f32x4 o0 = {e[0] * inv, e[1] * inv, e[2] * inv, e[3] * inv};
    f32x4 o1 = {e[4] * inv, e[5] * inv, e[6] * inv, e[7] * inv};
    __builtin_nontemporal_store(o0, &out4[(size_t)n * 16 + f * 2]);
    __builtin_nontemporal_store(o1, &out4[(size_t)n * 16 + f * 2 + 1]);
}

extern "C" void kernel_launch(void* const* d_in, const int* in_sizes, int n_in,
                              void* d_out, int out_size, void* d_ws, size_t ws_size,
                              hipStream_t stream) {
    const float* X = (const float*)d_in[0];
    const int* ei = (const int*)d_in[1];
    // d_in[2] = batch (unused)
    const float* Wn = (const float*)d_in[3];
    const float* bn = (const float*)d_in[4];
    const float* Ws = (const float*)d_in[5];
    const float* bs = (const float*)d_in[6];
    const float* Wf = (const float*)d_in[7];
    const float* bfu = (const float*)d_in[8];

    const int N = in_sizes[2];        // 100000
    const int E = in_sizes[1] / 2;    // 1600000
    const int* src = ei;
    const int* dst = ei + E;
    const int NB = (N + 255) >> 8;    // 391 buckets
    const int NBLK = (E + PCHUNK - 1) / PCHUNK;  // 782 chunk-blocks (<=1024 for rowscan)

    // workspace layout (same 33.2MB footprint)
    char* ws = (char*)d_ws;
    int* rowsum   = (int*)(ws + 0);            // NB*4; written by k_rowscan before any read
    int* bstart   = (int*)(ws + 12800);        // (NB+1)*4 -> pad 14464
    int* cnt      = (int*)(ws + 14464);        // 400000 -> 414464
    float* dinv   = (float*)(ws + 414464);     // 400000 -> 814464
    int* offs     = (int*)(ws + 814464);       // 400000 -> 1214464
    int* csr      = (int*)(ws + 1214464);      // 6400000 -> 7614464
    // rhist aliases csr: rhist dead (last read: k_part) before csr written (k_build).
    int* rhist    = (int*)(ws + 1214464);
    // slot A: ebuf (part/build, 4B/edge = 6.4MB), then aggXh (agg1 -> mlp)
    unsigned* ebuf = (unsigned*)(ws + 7614464);
    uint4* aggXh  = (uint4*)(ws + 7614464);
    // slot B: Xh (build-tail -> agg1), then Zs (mlp -> agg2)
    uint2* Xh     = (uint2*)(ws + 20414464);   // 12800000 -> 33214464 total
    _Float16* Zs  = (_Float16*)(ws + 20414464);

    k_bhist<<<NBLK, 256, 0, stream>>>(dst, E, N, rhist);
    k_rowscan<<<NB, 256, 0, stream>>>(rhist, NBLK, rowsum);
    k_nscan<<<1, 512, 0, stream>>>(rowsum, NB, E, bstart);
    k_part<<<NBLK, 256, 0, stream>>>(src, dst, E, N, rhist, bstart, ebuf);
    k_build<<<NB, 256, 0, stream>>>(ebuf, bstart, N, cnt, dinv, offs, csr,
                                    (const float4*)X, Xh);

    int gbl = (N * 8 + 255) / 256;  // 8 lanes per node
    k_agg1<<<gbl, 256, 0, stream>>>((const uint4*)Xh, dinv, offs, cnt, csr, N, aggXh);
    k_mlp<<<512, 256, 0, stream>>>((const _Float16*)aggXh, dinv, Wn, bn, Ws, bs, Wf, N, Zs);
    k_agg2<<<gbl, 256, 0, stream>>>((const uint4*)Zs, dinv, offs, cnt, csr,
                                    (const float4*)bfu, N, (f32x4*)d_out);
}